// Round 8
// baseline (483.618 us; speedup 1.0000x reference)
//
#include <hip/hip_runtime.h>
#include <hip/hip_bf16.h>

#define D_MODEL 4096
#define VOCAB 50257
#define NUM_SEQS 32
#define NT 1571   // ceil(VOCAB/32) vocab tiles of 32 rows
#define NSS 64    // super-steps (4 MFMA k-steps each; 64*4*16 = 4096 = K)

typedef __attribute__((ext_vector_type(8))) short bf16x8;
typedef __attribute__((ext_vector_type(16))) float f32x16;

// ws layout:
//   [0,128)              idx[32] int
//   [4096, +256KB)       hBh [512][32][8] short  (h hi bf16, MFMA-B-frag order)
//   [266240, +256KB)     hBl [512][32][8] short  (h lo bf16)
//   [528384, +402KB)     wbest [NT][32] u64 per-tile per-seq argmax keys

__device__ __forceinline__ void cvt2(float f, short* hi, short* lo) {
  union { __hip_bfloat16 b; short s; } h, l;
  h.b = __float2bfloat16(f);                 // RNE
  float hf = __bfloat162float(h.b);
  l.b = __float2bfloat16(f - hf);            // residual, RNE
  *hi = h.s; *lo = l.s;
}

__global__ void k_prep(const int* __restrict__ lens, int* __restrict__ idx) {
  if (threadIdx.x == 0) {
    int run = 0;
    for (int s = 0; s < NUM_SEQS; ++s) { run += lens[s]; idx[s] = run - 1; }
  }
}

// 256 blocks x 512: thread g -> (s = g>>12, k = g&4095). Coalesced hs reads.
__global__ void k_gather(const float* __restrict__ hs, const int* __restrict__ idx,
                         short* __restrict__ hBh, short* __restrict__ hBl) {
  int g = blockIdx.x * 512 + threadIdx.x;
  int s = g >> 12, k = g & 4095;
  float v = hs[(size_t)idx[s] * D_MODEL + k];
  short hi, lo; cvt2(v, &hi, &lo);
  int off = ((k >> 3) * 32 + s) * 8 + (k & 7);  // [k/8][s][k%8]
  hBh[off] = hi; hBl[off] = lo;
}

// One super-step: consume 4 MFMA k-steps from (A,Bh,Bl), refilling the same
// slots with super-step data at k-step base `tref` (issued B-first). Data
// consumed here was issued TWO super-steps ago (ping-pong X/Y), so the
// vmcnt wait always leaves ~2 super-steps of loads (32 KB/wave) in flight.
__device__ __forceinline__ void super_step(
    const float4* __restrict__ wr, const short* __restrict__ bph,
    const short* __restrict__ bpl, float4 (&A)[8], bf16x8 (&Bh)[4],
    bf16x8 (&Bl)[4], int tref, f32x16& accA, f32x16& accB) {
#pragma unroll
  for (int j = 0; j < 4; ++j) {
    bf16x8 bh = Bh[j], bl = Bl[j];
    float4 a0 = A[2 * j], a1 = A[2 * j + 1];
    // refill slots (B before A; addresses compile-time offsets from tref)
    Bh[j] = *(const bf16x8*)(bph + 512 * (tref + j));
    Bl[j] = *(const bf16x8*)(bpl + 512 * (tref + j));
    A[2 * j]     = wr[4 * (tref + j)];
    A[2 * j + 1] = wr[4 * (tref + j) + 1];
    // f32 -> bf16 hi/lo split of the A fragment (static indexing only)
    float fa[8] = {a0.x, a0.y, a0.z, a0.w, a1.x, a1.y, a1.z, a1.w};
    bf16x8 ahi, alo;
#pragma unroll
    for (int e = 0; e < 8; ++e) {
      short hi, lo; cvt2(fa[e], &hi, &lo);
      ahi[e] = hi; alo[e] = lo;
    }
    accA = __builtin_amdgcn_mfma_f32_32x32x16_bf16(ahi, bh, accA, 0, 0, 0);
    accB = __builtin_amdgcn_mfma_f32_32x32x16_bf16(ahi, bl, accB, 0, 0, 0);
    accA = __builtin_amdgcn_mfma_f32_32x32x16_bf16(alo, bh, accA, 0, 0, 0);
  }
}

// grid NT x 64. One wave per block: one 32-vocab x 32-seq tile, full K=4096.
__global__ __launch_bounds__(64) void k_mfma(const float* __restrict__ W,
    const short* __restrict__ hBh, const short* __restrict__ hBl,
    unsigned long long* __restrict__ wbest) {
  const int lane = threadIdx.x;
  const int half = lane >> 5;
  const int r32 = lane & 31;
  const int tile = blockIdx.x;
  const int wrow = min(tile * 32 + r32, VOCAB - 1);
  const float4* wr = (const float4*)(W + (size_t)wrow * D_MODEL + half * 8);
  const short* bph = hBh + ((size_t)half * 32 + r32) * 8;  // k-step stride 512
  const short* bpl = hBl + ((size_t)half * 32 + r32) * 8;

  f32x16 accA, accB;
#pragma unroll
  for (int i = 0; i < 16; ++i) { accA[i] = 0.f; accB[i] = 0.f; }

  float4 Ax[8], Ay[8];
  bf16x8 Bhx[4], Blx[4], Bhy[4], Bly[4];

  // prologue: super-step 0 -> X, super-step 1 -> Y (B before A in each)
#pragma unroll
  for (int j = 0; j < 4; ++j) {
    Bhx[j] = *(const bf16x8*)(bph + 512 * j);
    Blx[j] = *(const bf16x8*)(bpl + 512 * j);
  }
#pragma unroll
  for (int j = 0; j < 4; ++j) { Ax[2 * j] = wr[4 * j]; Ax[2 * j + 1] = wr[4 * j + 1]; }
#pragma unroll
  for (int j = 0; j < 4; ++j) {
    Bhy[j] = *(const bf16x8*)(bph + 512 * (4 + j));
    Bly[j] = *(const bf16x8*)(bpl + 512 * (4 + j));
  }
#pragma unroll
  for (int j = 0; j < 4; ++j) {
    Ay[2 * j] = wr[4 * (4 + j)]; Ay[2 * j + 1] = wr[4 * (4 + j) + 1];
  }

#pragma unroll 1
  for (int ss = 0; ss < NSS / 2; ++ss) {
    const int tx = 2 * ss, ty = 2 * ss + 1;
    const int rx = (tx + 2 < NSS) ? (tx + 2) * 4 : 0;  // wrap: harmless re-read
    const int ry = (ty + 2 < NSS) ? (ty + 2) * 4 : 0;
    super_step(wr, bph, bpl, Ax, Bhx, Blx, rx, accA, accB);
    super_step(wr, bph, bpl, Ay, Bhy, Bly, ry, accA, accB);
  }

#pragma unroll
  for (int i = 0; i < 16; ++i) accA[i] += accB[i];

  // C layout: col(seq)=lane&31, row=(r&3)+8*(r>>2)+4*half
  unsigned long long best = 0ull;
#pragma unroll
  for (int r = 0; r < 16; ++r) {
    int row = (r & 3) + 8 * (r >> 2) + 4 * half;
    int v = tile * 32 + row;
    if (v < VOCAB) {
      unsigned u = __float_as_uint(accA[r]);
      u = (u & 0x80000000u) ? ~u : (u | 0x80000000u);
      unsigned long long key = ((unsigned long long)u << 32) | (unsigned)(~v);
      if (key > best) best = key;
    }
  }
  unsigned long long o = __shfl_xor(best, 32, 64);
  if (o > best) best = o;
  if (half == 0) wbest[(size_t)tile * 32 + r32] = best;  // lane r32 = seq r32
}

// 32 blocks x 256: block = seq; scan NT tile-keys, first-occurrence tie-break.
__global__ __launch_bounds__(256) void k_final(
    const unsigned long long* __restrict__ wbest, int* __restrict__ out) {
  int s = blockIdx.x;
  unsigned long long best = 0ull;
  for (int i = threadIdx.x; i < NT; i += 256) {
    unsigned long long k = wbest[(size_t)i * 32 + s];
    if (k > best) best = k;
  }
#pragma unroll
  for (int off = 32; off > 0; off >>= 1) {
    unsigned long long o = __shfl_xor(best, off, 64);
    if (o > best) best = o;
  }
  __shared__ unsigned long long lred[4];
  if ((threadIdx.x & 63) == 0) lred[threadIdx.x >> 6] = best;
  __syncthreads();
  if (threadIdx.x == 0) {
#pragma unroll
    for (int i = 1; i < 4; ++i) if (lred[i] > best) best = lred[i];
    out[s] = (int)(~(unsigned)(best & 0xFFFFFFFFull));
  }
}

extern "C" void kernel_launch(void* const* d_in, const int* in_sizes, int n_in,
                              void* d_out, int out_size, void* d_ws, size_t ws_size,
                              hipStream_t stream) {
  const float* hs  = (const float*)d_in[0];   // [16384][4096] f32
  const float* W   = (const float*)d_in[1];   // [50257][4096] f32
  const int* lens  = (const int*)d_in[2];     // [32] i32

  char* ws = (char*)d_ws;
  int* idx = (int*)ws;
  short* hBh = (short*)(ws + 4096);
  short* hBl = (short*)(ws + 266240);
  unsigned long long* wbest = (unsigned long long*)(ws + 528384);
  int* out = (int*)d_out;

  k_prep<<<1, 64, 0, stream>>>(lens, idx);
  k_gather<<<256, 512, 0, stream>>>(hs, idx, hBh, hBl);
  k_mfma<<<NT, 64, 0, stream>>>(W, hBh, hBl, wbest);
  k_final<<<NUM_SEQS, 256, 0, stream>>>(wbest, out);
}

// Round 9
// 255.890 us; speedup vs baseline: 1.8899x; 1.8899x over previous
//
#include <hip/hip_runtime.h>
#include <hip/hip_bf16.h>

#define D_MODEL 4096
#define VOCAB 50257
#define NUM_SEQS 32
#define NT 1571    // ceil(VOCAB/32) vocab tiles of 32 rows
#define KSP 4      // K-split: waves per tile
#define KW (D_MODEL / KSP)     // 1024 K per wave
#define TSTEPS (KW / 16)       // 64 MFMA k-steps per wave

typedef __attribute__((ext_vector_type(8))) short bf16x8;
typedef __attribute__((ext_vector_type(16))) float f32x16;

// ws layout:
//   [0,128)              idx[32] int
//   [4096, +256KB)       hBh [512][32][8] short  (h hi bf16, MFMA-B-frag order)
//   [266240, +256KB)     hBl [512][32][8] short  (h lo bf16)
//   [528384, +402KB)     wbest [NT][32] u64 per-tile per-seq argmax keys
//   [1MB, +25.7MB)       part [KSP][NT][32][32] f32 partial C tiles

__device__ __forceinline__ void cvt2(float f, short* hi, short* lo) {
  union { __hip_bfloat16 b; short s; } h, l;
  h.b = __float2bfloat16(f);                 // RNE
  float hf = __bfloat162float(h.b);
  l.b = __float2bfloat16(f - hf);            // residual, RNE
  *hi = h.s; *lo = l.s;
}

__global__ void k_prep(const int* __restrict__ lens, int* __restrict__ idx) {
  if (threadIdx.x == 0) {
    int run = 0;
    for (int s = 0; s < NUM_SEQS; ++s) { run += lens[s]; idx[s] = run - 1; }
  }
}

// 256 blocks x 512: thread g -> (s = g>>12, k = g&4095). Coalesced hs reads.
__global__ void k_gather(const float* __restrict__ hs, const int* __restrict__ idx,
                         short* __restrict__ hBh, short* __restrict__ hBl) {
  int g = blockIdx.x * 512 + threadIdx.x;
  int s = g >> 12, k = g & 4095;
  float v = hs[(size_t)idx[s] * D_MODEL + k];
  short hi, lo; cvt2(v, &hi, &lo);
  int off = ((k >> 3) * 32 + s) * 8 + (k & 7);  // [k/8][s][k%8]
  hBh[off] = hi; hBl[off] = lo;
}

// grid (NT, KSP) x 64. One wave per block: K-chunk [blockIdx.y*1024, +1024) of
// one 32-vocab x 32-seq tile. EXACT r5 inner loop (depth-2 A roll, depth-1 B)
// -- the compiler schedules this well; deeper hand-pipelines all regressed.
// Writes raw partial C tile to its own plane (no atomics, no sync).
__global__ __launch_bounds__(64) void k_mfma(const float* __restrict__ W,
    const short* __restrict__ hBh, const short* __restrict__ hBl,
    float* __restrict__ part) {
  const int lane = threadIdx.x;
  const int half = lane >> 5;
  const int r32 = lane & 31;
  const int tile = blockIdx.x;
  const int kq = blockIdx.y;
  const int k0 = kq * KW;
  const int wrow = min(tile * 32 + r32, VOCAB - 1);
  const float* wp = W + (size_t)wrow * D_MODEL + k0 + half * 8;
  const short* bph = hBh + (((size_t)(k0 >> 3) + half) * 32 + r32) * 8;
  const short* bpl = hBl + (((size_t)(k0 >> 3) + half) * 32 + r32) * 8;

  f32x16 accA, accB;
#pragma unroll
  for (int i = 0; i < 16; ++i) { accA[i] = 0.f; accB[i] = 0.f; }

  // A prefetch depth 2 (HBM stream), B depth 1 (L2 stream)
  float4 a0 = *(const float4*)(wp);
  float4 a1 = *(const float4*)(wp + 4);
  float4 p0 = *(const float4*)(wp + 16);
  float4 p1 = *(const float4*)(wp + 20);
  bf16x8 bh = *(const bf16x8*)(bph);
  bf16x8 bl = *(const bf16x8*)(bpl);

#pragma unroll 1
  for (int t = 0; t < TSTEPS; ++t) {
    const int t2 = (t + 2 < TSTEPS) ? t + 2 : 0;
    const int t1 = (t + 1 < TSTEPS) ? t + 1 : 0;
    float4 n0 = *(const float4*)(wp + 16 * t2);
    float4 n1 = *(const float4*)(wp + 16 * t2 + 4);
    bf16x8 nbh = *(const bf16x8*)(bph + 512 * t1);
    bf16x8 nbl = *(const bf16x8*)(bpl + 512 * t1);

    float fa[8] = {a0.x, a0.y, a0.z, a0.w, a1.x, a1.y, a1.z, a1.w};
    bf16x8 ahi, alo;
#pragma unroll
    for (int e = 0; e < 8; ++e) {
      short hi, lo; cvt2(fa[e], &hi, &lo);
      ahi[e] = hi; alo[e] = lo;
    }

    accA = __builtin_amdgcn_mfma_f32_32x32x16_bf16(ahi, bh, accA, 0, 0, 0);
    accB = __builtin_amdgcn_mfma_f32_32x32x16_bf16(ahi, bl, accB, 0, 0, 0);
    accA = __builtin_amdgcn_mfma_f32_32x32x16_bf16(alo, bh, accA, 0, 0, 0);

    a0 = p0; a1 = p1; p0 = n0; p1 = n1; bh = nbh; bl = nbl;
  }

  // write raw partial tile: part[kq][tile][row][col]; coalesced 128B segments
  float* pc = part + ((size_t)kq * NT + tile) * 1024;
#pragma unroll
  for (int r = 0; r < 16; ++r) {
    int row = (r & 3) + 8 * (r >> 2) + 4 * half;  // C layout row
    pc[row * 32 + r32] = accA[r] + accB[r];
  }
}

// NT blocks x 64. Lane l: seq s=l&31, rows (l>>5)*16..+16. Sums KSP planes in
// fixed order (deterministic), per-seq argmax key with first-occurrence tie-break.
__global__ __launch_bounds__(64) void k_reduce(const float* __restrict__ part,
                                               unsigned long long* __restrict__ wbest) {
  const int tile = blockIdx.x;
  const int l = threadIdx.x;
  const int s = l & 31;
  const int rbase = (l >> 5) * 16;
  const float* p0 = part + (size_t)tile * 1024;

  unsigned long long best = 0ull;
#pragma unroll
  for (int r = 0; r < 16; ++r) {
    const int row = rbase + r;
    const int v = tile * 32 + row;
    float x = 0.f;
#pragma unroll
    for (int q = 0; q < KSP; ++q)
      x += p0[(size_t)q * NT * 1024 + row * 32 + s];
    if (v < VOCAB) {
      unsigned u = __float_as_uint(x);
      u = (u & 0x80000000u) ? ~u : (u | 0x80000000u);
      unsigned long long key = ((unsigned long long)u << 32) | (unsigned)(~v);
      if (key > best) best = key;
    }
  }
  unsigned long long o = __shfl_xor(best, 32, 64);
  if (o > best) best = o;
  if (l < 32) wbest[(size_t)tile * 32 + s] = best;
}

// 32 blocks x 256: block = seq; scan NT tile-keys, first-occurrence tie-break.
__global__ __launch_bounds__(256) void k_final(
    const unsigned long long* __restrict__ wbest, int* __restrict__ out) {
  int s = blockIdx.x;
  unsigned long long best = 0ull;
  for (int i = threadIdx.x; i < NT; i += 256) {
    unsigned long long k = wbest[(size_t)i * 32 + s];
    if (k > best) best = k;
  }
#pragma unroll
  for (int off = 32; off > 0; off >>= 1) {
    unsigned long long o = __shfl_xor(best, off, 64);
    if (o > best) best = o;
  }
  __shared__ unsigned long long lred[4];
  if ((threadIdx.x & 63) == 0) lred[threadIdx.x >> 6] = best;
  __syncthreads();
  if (threadIdx.x == 0) {
#pragma unroll
    for (int i = 1; i < 4; ++i) if (lred[i] > best) best = lred[i];
    out[s] = (int)(~(unsigned)(best & 0xFFFFFFFFull));
  }
}

extern "C" void kernel_launch(void* const* d_in, const int* in_sizes, int n_in,
                              void* d_out, int out_size, void* d_ws, size_t ws_size,
                              hipStream_t stream) {
  const float* hs  = (const float*)d_in[0];   // [16384][4096] f32
  const float* W   = (const float*)d_in[1];   // [50257][4096] f32
  const int* lens  = (const int*)d_in[2];     // [32] i32

  char* ws = (char*)d_ws;
  int* idx = (int*)ws;
  short* hBh = (short*)(ws + 4096);
  short* hBl = (short*)(ws + 266240);
  unsigned long long* wbest = (unsigned long long*)(ws + 528384);
  float* part = (float*)(ws + (1 << 20));
  int* out = (int*)d_out;

  k_prep<<<1, 64, 0, stream>>>(lens, idx);
  k_gather<<<256, 512, 0, stream>>>(hs, idx, hBh, hBl);
  dim3 grid(NT, KSP);
  k_mfma<<<grid, 64, 0, stream>>>(W, hBh, hBl, part);
  k_reduce<<<NT, 64, 0, stream>>>(part, wbest);
  k_final<<<NUM_SEQS, 256, 0, stream>>>(wbest, out);
}